// Round 9
// baseline (284.211 us; speedup 1.0000x reference)
//
#include <hip/hip_runtime.h>
#include <hip/hip_bf16.h>

#define BATCH 8
#define NQ 3136
#define CDIM 128
#define NHEAD 4
#define HD 32
#define NKV 784
#define NKVP 896          // padded kv extent (7*128)
#define HIMG 56
#define SCALE 0.17677669529663687f
#define L2E 1.44269504f
#define NQT16 196         // NQ/16
#define NCT 56            // padded kv tiles (NKVP/16)

typedef __attribute__((ext_vector_type(8))) short bf8_t;   // 8 x bf16 (4 VGPRs)
typedef __attribute__((ext_vector_type(4))) float f4_t;    // 4 x fp32

using bf16 = __hip_bfloat16;
using u16  = unsigned short;

static __device__ __forceinline__ float b2f(bf16 v){ return __bfloat162float(v); }
static __device__ __forceinline__ bf16  f2b(float v){ return __float2bfloat16(v); }
static __device__ __forceinline__ short f2s(float v){
  union { bf16 b; short s; } u; u.b = f2b(v); return u.s;
}
static __device__ __forceinline__ float ld1(const void* p, size_t i, int f){
  return f ? b2f(((const bf16*)p)[i]) : ((const float*)p)[i];
}
static __device__ __forceinline__ bf8_t ld8(const void* p, size_t i, int f){
  if (f) return *(const bf8_t*)((const bf16*)p + i);
  const float* fp = (const float*)p + i;
  float4 a = *(const float4*)fp;
  float4 b = *(const float4*)(fp + 4);
  bf8_t r;
  r[0]=f2s(a.x); r[1]=f2s(a.y); r[2]=f2s(a.z); r[3]=f2s(a.w);
  r[4]=f2s(b.x); r[5]=f2s(b.y); r[6]=f2s(b.z); r[7]=f2s(b.w);
  return r;
}
static __device__ __forceinline__ int detect_flag(const void* var_raw){
  const u16* h = (const u16*)var_raw;
  int lane = threadIdx.x & 63;
  bool ok = true;
  #pragma unroll
  for (int t = 0; t < 2; t++){
    union { u16 u; bf16 b; } cv; cv.u = h[lane + 64*t];
    float v = b2f(cv.b);
    ok = ok && (v > 0.3f) && (v < 1.7f);
  }
  return (__ballot(ok) == ~0ull) ? 1 : 0;
}

static __device__ __forceinline__ void mfma_row(
    const bf8_t a[4], const bf16* __restrict__ Wt, int m, int g, f4_t acc[8])
{
  #pragma unroll
  for (int ct = 0; ct < 8; ct++){
    f4_t c = {0.f,0.f,0.f,0.f};
    const bf16* bp = Wt + (size_t)(ct*16 + m)*CDIM + 8*g;
    #pragma unroll
    for (int ks = 0; ks < 4; ks++){
      bf8_t b = *(const bf8_t*)(bp + 32*ks);
      c = __builtin_amdgcn_mfma_f32_16x16x32_bf16(a[ks], b, c, 0,0,0);
    }
    acc[ct] = c;
  }
}

// ---------------------------------------------------------------------------
// prep: weight transposes; Wqt/bqs carry SCALE*L2E; small params; BN fold.
// ---------------------------------------------------------------------------
__global__ __launch_bounds__(256) void prep_kernel(
    const void* __restrict__ Wq, const void* __restrict__ Wk,
    const void* __restrict__ Wv, const void* __restrict__ Wp,
    const void* __restrict__ var, const void* __restrict__ cw,
    const void* __restrict__ cb, const void* __restrict__ gam,
    const void* __restrict__ bet, const void* __restrict__ mea,
    const void* __restrict__ bq, const void* __restrict__ bk,
    const void* __restrict__ bv, const void* __restrict__ bp,
    bf16* __restrict__ Wqt, bf16* __restrict__ Wkt,
    bf16* __restrict__ Wvt, bf16* __restrict__ Wpt,
    bf16* __restrict__ bqs, bf16* __restrict__ bks,
    bf16* __restrict__ bvs, bf16* __restrict__ bps,
    float* __restrict__ cwf, float* __restrict__ inv, float* __restrict__ shift2)
{
  int f = detect_flag(var);
  int idx = blockIdx.x*256 + threadIdx.x;
  int mat = idx >> 14;
  int e   = idx & 16383;
  int o = e >> 7, i = e & 127;
  const void* src; bf16* dst; float s = 1.f;
  if      (mat == 0){ src = Wq; dst = Wqt; s = SCALE * L2E; }
  else if (mat == 1){ src = Wk; dst = Wkt; }
  else if (mat == 2){ src = Wv; dst = Wvt; }
  else              { src = Wp; dst = Wpt; }
  dst[e] = f2b(ld1(src, (size_t)i*128 + o, f) * s);

  if (blockIdx.x == 0){
    int t = threadIdx.x;
    cwf[t]       = ld1(cw, t, f);
    cwf[t + 256] = ld1(cw, t + 256, f);
    if (t < 128){
      bqs[t] = f2b(ld1(bq, t, f) * SCALE * L2E);
      bks[t] = f2b(ld1(bk, t, f));
      bvs[t] = f2b(ld1(bv, t, f));
      bps[t] = f2b(ld1(bp, t, f));
      float iv = ld1(gam, t, f) * rsqrtf(ld1(var, t, f) + 1e-5f);
      inv[t] = iv;
      shift2[t] = ld1(bet, t, f) - ld1(mea, t, f) * iv + ld1(cb, t, f) * iv;
    }
  }
}

// ---------------------------------------------------------------------------
// fat: [0,3136) spatial reduction -> xr ; [3136,3528) Q-proj -> qbf
// ---------------------------------------------------------------------------
__global__ __launch_bounds__(256) void fat_kernel(
    const void* __restrict__ x, const void* __restrict__ var,
    const float* __restrict__ cwf, const float* __restrict__ inv,
    const float* __restrict__ shift2, bf16* __restrict__ xr,
    const bf16* __restrict__ Wqt, const bf16* __restrict__ bqs,
    bf16* __restrict__ qbf)
{
  int f = detect_flag(var);
  if (blockIdx.x < 3136){
    int idx = blockIdx.x*256 + threadIdx.x;
    int c  = idx & 127;
    int t  = idx >> 7;
    int b  = t / NKV;
    int kv = t - b*NKV;
    int i = kv/28, j = kv - i*28;
    size_t base = (size_t)(b*NQ + 2*i*HIMG + 2*j)*CDIM + c;
    float acc = ld1(x, base, f)                   * cwf[c*4 + 0]
              + ld1(x, base + CDIM, f)            * cwf[c*4 + 1]
              + ld1(x, base + HIMG*CDIM, f)       * cwf[c*4 + 2]
              + ld1(x, base + HIMG*CDIM + CDIM, f)* cwf[c*4 + 3];
    xr[idx] = f2b(acc * inv[c] + shift2[c]);
  } else {
    int wave = threadIdx.x >> 6, lane = threadIdx.x & 63;
    int m = lane & 15, g = lane >> 4;
    int task = (blockIdx.x - 3136)*4 + wave;
    int row0 = task*16;
    bf8_t a[4];
    #pragma unroll
    for (int ks = 0; ks < 4; ks++)
      a[ks] = ld8(x, (size_t)(row0 + m)*CDIM + 8*g + 32*ks, f);
    f4_t acc[8];
    mfma_row(a, Wqt, m, g, acc);
    #pragma unroll
    for (int ct = 0; ct < 8; ct++){
      int col = ct*16 + m;
      float bv = b2f(bqs[col]);
      #pragma unroll
      for (int r = 0; r < 4; r++)
        qbf[(size_t)(row0 + 4*g + r)*CDIM + col] = f2b(acc[ct][r] + bv);
    }
  }
}

// ---------------------------------------------------------------------------
// rel transform: one block per (h, qtile16). Coalesced global reads -> LDS
// (bf16, *L2E, cols 784..895 filled with -3.4e38) -> C-fragment-ordered
// relb tiles (56 per qtile, coalesced uint2 writes).
// relb[((h*196+t16)*56 + c16)*256 + lane*4 + r] = rel[h][t16*16+4g+r][c16*16+m]*L2E
// ---------------------------------------------------------------------------
__global__ __launch_bounds__(256) void rel_kernel(
    const void* __restrict__ rel, const void* __restrict__ var,
    bf16* __restrict__ relb)
{
  int f = detect_flag(var);
  int h   = blockIdx.x / NQT16;
  int t16 = blockIdx.x - h*NQT16;
  int tid = threadIdx.x;
  __shared__ u16 srel[16*NKVP];   // 28 KB

  if (f){
    // bf16 input: 98 uint4 units (8 els) per row
    for (int u = tid; u < 16*98; u += 256){
      int row = u / 98, c8 = u - row*98;
      const bf16* gp = (const bf16*)rel + ((size_t)h*NQ + t16*16 + row)*NKV + c8*8;
      union { uint4 q; u16 hh[8]; } in; in.q = *(const uint4*)gp;
      u16* dp = srel + row*NKVP + c8*8;
      #pragma unroll
      for (int e = 0; e < 8; e++){
        union { unsigned u; float ff; } cv; cv.u = ((unsigned)in.hh[e]) << 16;
        dp[e] = (u16)f2s(cv.ff * L2E);
      }
    }
  } else {
    // fp32 input: 196 float4 units per row
    for (int u = tid; u < 16*196; u += 256){
      int row = u / 196, c4 = u - row*196;
      const float* gp = (const float*)rel + ((size_t)h*NQ + t16*16 + row)*NKV + c4*4;
      float4 v = *(const float4*)gp;
      u16* dp = srel + row*NKVP + c4*4;
      dp[0] = (u16)f2s(v.x*L2E); dp[1] = (u16)f2s(v.y*L2E);
      dp[2] = (u16)f2s(v.z*L2E); dp[3] = (u16)f2s(v.w*L2E);
    }
  }
  // pad cols 784..895 = -3.39e38 (bf16 0xFF7F) -> exp2 -> 0
  for (int u = tid; u < 16*28; u += 256){
    int row = u / 28, c4 = u - row*28;
    *(uint2*)(srel + row*NKVP + 784 + c4*4) = make_uint2(0xFF7FFF7Fu, 0xFF7FFF7Fu);
  }
  __syncthreads();

  bf16* outb = relb + (size_t)(h*NQT16 + t16)*NCT*256;
  for (int u = tid; u < NCT*64; u += 256){
    int tile = u >> 6, ln = u & 63;
    int mm = ln & 15, gg = ln >> 4;
    const u16* sp = srel + (4*gg)*NKVP + tile*16 + mm;
    union { u16 hh[4]; uint2 q; } pk;
    #pragma unroll
    for (int r = 0; r < 4; r++) pk.hh[r] = sp[r*NKVP];
    *(uint2*)(outb + (size_t)u*4) = pk.q;
  }
}

// ---------------------------------------------------------------------------
// kv: [0,98) K-proj -> kbf2 (b,896,128); [98,196) V-proj -> vtb2 (b,h,d)x896;
//     [196,224) zero-fill the kv pads of both (needed: first call ws is raw).
// ---------------------------------------------------------------------------
__global__ __launch_bounds__(256) void kv_kernel(
    const bf16* __restrict__ xr,
    const bf16* __restrict__ Wkt, const bf16* __restrict__ Wvt,
    const bf16* __restrict__ bks, const bf16* __restrict__ bvs,
    bf16* __restrict__ kbf2, bf16* __restrict__ vtb2)
{
  if (blockIdx.x >= 196){
    int u0 = (blockIdx.x - 196)*256 + threadIdx.x;   // uint4 units, x4
    #pragma unroll
    for (int j = 0; j < 4; j++){
      int u = u0*4 + j;                              // 0..28671
      bf16* p;
      if (u < 14336){                                // kbf2 pads: 16 units/row
        int b = u / 1792, r = u - b*1792;
        int row = r >> 4, cu = r & 15;
        p = kbf2 + (size_t)(b*NKVP + 784 + row)*CDIM + cu*8;
      } else {                                       // vtb2 pads: 14 units/row
        int v = u - 14336;
        int row = v / 14, cu = v - row*14;
        p = vtb2 + (size_t)row*NKVP + 784 + cu*8;
      }
      *(uint4*)p = make_uint4(0,0,0,0);
    }
    return;
  }
  int wave = threadIdx.x >> 6, lane = threadIdx.x & 63;
  int m = lane & 15, g = lane >> 4;
  bool isK = blockIdx.x < 98;
  int bx = isK ? blockIdx.x : blockIdx.x - 98;
  int row0 = (bx*4 + wave)*16;
  bf8_t a[4];
  #pragma unroll
  for (int ks = 0; ks < 4; ks++)
    a[ks] = *(const bf8_t*)(xr + (size_t)(row0 + m)*CDIM + 8*g + 32*ks);
  f4_t acc[8];
  mfma_row(a, isK ? Wkt : Wvt, m, g, acc);

  int b   = row0 / NKV;
  int kvr = row0 - b*NKV;
  if (isK){
    #pragma unroll
    for (int ct = 0; ct < 8; ct++){
      int col = ct*16 + m;
      float bv = b2f(bks[col]);
      #pragma unroll
      for (int r = 0; r < 4; r++)
        kbf2[(size_t)(b*NKVP + kvr + 4*g + r)*CDIM + col] = f2b(acc[ct][r] + bv);
    }
  } else {
    int kv0 = kvr + 4*g;
    #pragma unroll
    for (int ct = 0; ct < 8; ct++){
      int col = ct*16 + m;
      float bv = b2f(bvs[col]);
      int h = col >> 5, d = col & 31;
      union { bf16 hh[4]; uint2 u; } pk;
      #pragma unroll
      for (int r = 0; r < 4; r++) pk.hh[r] = f2b(acc[ct][r] + bv);
      *(uint2*)(vtb2 + (size_t)((b*NHEAD + h)*HD + d)*NKVP + kv0) = pk.u;
    }
  }
}

// ---------------------------------------------------------------------------
// attention, pipelined: 7 uniform 128-kv chunks; rolling register prefetch of
// next chunk's K-frags + rel-frags; single wave-private P-LDS (no barriers);
// rel enters QK as the MFMA C-operand (log2 domain); p = exp2(s).
// Pads (kv>=784): K=0, rel=-3.4e38 -> p=0; V=0.
// ---------------------------------------------------------------------------
template<int QF>
__global__ __launch_bounds__(256) void attn_kernel(
    const bf16* __restrict__ qbf, const void* __restrict__ x,
    const bf16* __restrict__ Wqt, const bf16* __restrict__ bqs,
    const bf16* __restrict__ kb2, const bf16* __restrict__ vtb2,
    const bf16* __restrict__ relb, const void* __restrict__ var,
    void* __restrict__ dout, bf16* __restrict__ obf)
{
  int f = detect_flag(var);
  int wave = threadIdx.x >> 6, lane = threadIdx.x & 63;
  int m = lane & 15, g = lane >> 4;
  int b = blockIdx.z, h = blockIdx.y, qt = blockIdx.x;
  int qrow0 = qt*64 + wave*16;

  __shared__ bf16 Plds[4][16*136];
  bf16* pl = Plds[wave];

  bf8_t q8;
  if constexpr (QF == 0){
    q8 = *(const bf8_t*)(qbf + (size_t)(b*NQ + qrow0 + m)*CDIM + h*HD + 8*g);
  } else {
    bf8_t xa[4];
    #pragma unroll
    for (int ks = 0; ks < 4; ks++)
      xa[ks] = ld8(x, (size_t)(b*NQ + qrow0 + m)*CDIM + 8*g + 32*ks, f);
    f4_t qc0 = {0.f,0.f,0.f,0.f}, qc1 = {0.f,0.f,0.f,0.f};
    const bf16* wp0 = Wqt + (size_t)(h*HD + m)*CDIM + 8*g;
    const bf16* wp1 = Wqt + (size_t)(h*HD + 16 + m)*CDIM + 8*g;
    #pragma unroll
    for (int ks = 0; ks < 4; ks++){
      bf8_t w0 = *(const bf8_t*)(wp0 + 32*ks);
      bf8_t w1 = *(const bf8_t*)(wp1 + 32*ks);
      qc0 = __builtin_amdgcn_mfma_f32_16x16x32_bf16(xa[ks], w0, qc0, 0,0,0);
      qc1 = __builtin_amdgcn_mfma_f32_16x16x32_bf16(xa[ks], w1, qc1, 0,0,0);
    }
    float bv0 = b2f(bqs[h*HD + m]);
    float bv1 = b2f(bqs[h*HD + 16 + m]);
    #pragma unroll
    for (int r = 0; r < 4; r++){
      pl[(4*g + r)*136 + m]      = f2b(qc0[r] + bv0);
      pl[(4*g + r)*136 + 16 + m] = f2b(qc1[r] + bv1);
    }
    q8 = *(const bf8_t*)(pl + m*136 + 8*g);
  }

  const bf16* kbase = kb2 + (size_t)(b*NKVP + m)*CDIM + h*HD + 8*g;
  const bf16* vb0   = vtb2 + (size_t)((b*NHEAD + h)*HD + m)*NKVP;
  const bf16* vb1   = vb0 + (size_t)16*NKVP;
  const bf16* relt  = relb + (size_t)(h*NQT16 + (qrow0 >> 4))*NCT*256;

  float l_run[4] = {0.f,0.f,0.f,0.f};
  f4_t O0 = {0.f,0.f,0.f,0.f}, O1 = {0.f,0.f,0.f,0.f};

  bf8_t kc[8]; uint2 rl[8];
  #pragma unroll
  for (int t = 0; t < 8; t++){
    kc[t] = *(const bf8_t*)(kbase + (size_t)(t*16)*CDIM);
    rl[t] = *(const uint2*)(relt + (size_t)(t*64 + lane)*4);
  }

  #pragma unroll 1
  for (int c = 0; c < 7; c++){
    int cn = (c < 6) ? c + 1 : 6;      // clamped prefetch (last re-loads ch.6)
    bf8_t kn[8]; uint2 rn[8];
    #pragma unroll
    for (int t = 0; t < 8; t++){
      kn[t] = *(const bf8_t*)(kbase + (size_t)(cn*128 + t*16)*CDIM);
      rn[t] = *(const uint2*)(relt + (size_t)((cn*8 + t)*64 + lane)*4);
    }
    int kv0 = c*128;
    #pragma unroll
    for (int t = 0; t < 8; t++){
      f4_t rc;
      rc[0] = __uint_as_float(rl[t].x << 16);
      rc[1] = __uint_as_float(rl[t].x & 0xffff0000u);
      rc[2] = __uint_as_float(rl[t].y << 16);
      rc[3] = __uint_as_float(rl[t].y & 0xffff0000u);
      f4_t s = __builtin_amdgcn_mfma_f32_16x16x32_bf16(q8, kc[t], rc, 0,0,0);
      #pragma unroll
      for (int r = 0; r < 4; r++){
        float p = exp2f(s[r]);
        l_run[r] += p;
        pl[(4*g + r)*136 + t*16 + m] = f2b(p);
      }
    }
    #pragma unroll
    for (int ks = 0; ks < 4; ks++){
      bf8_t a8 = *(const bf8_t*)(pl + m*136 + ks*32 + 8*g);
      bf8_t v0 = *(const bf8_t*)(vb0 + kv0 + ks*32 + 8*g);
      bf8_t v1 = *(const bf8_t*)(vb1 + kv0 + ks*32 + 8*g);
      O0 = __builtin_amdgcn_mfma_f32_16x16x32_bf16(a8, v0, O0, 0,0,0);
      O1 = __builtin_amdgcn_mfma_f32_16x16x32_bf16(a8, v1, O1, 0,0,0);
    }
    #pragma unroll
    for (int t = 0; t < 8; t++){ kc[t] = kn[t]; rl[t] = rn[t]; }
  }

  #pragma unroll
  for (int xm = 1; xm < 16; xm <<= 1){
    #pragma unroll
    for (int r = 0; r < 4; r++)
      l_run[r] += __shfl_xor(l_run[r], xm, 64);
  }
  bf16* ob = f ? (bf16*)dout : obf;
  size_t orow = (size_t)(b*NQ + qrow0 + 4*g);
  #pragma unroll
  for (int r = 0; r < 4; r++){
    float iv = 1.0f / l_run[r];
    ob[(orow + r)*CDIM + h*HD + m]      = f2b(O0[r] * iv);
    ob[(orow + r)*CDIM + h*HD + 16 + m] = f2b(O1[r] * iv);
  }
}

// ---------------------------------------------------------------------------
// final projection: in-place (bf16 mode) | obf -> fp32 d_out (fp32 mode).
// ---------------------------------------------------------------------------
__global__ __launch_bounds__(256) void proj_kernel(
    const bf16* A0, const bf16* A1, const bf16* __restrict__ Wt,
    const bf16* __restrict__ bias, void* outp, const void* __restrict__ var)
{
  int f = detect_flag(var);
  const bf16* A = f ? A0 : A1;
  int wave = threadIdx.x >> 6, lane = threadIdx.x & 63;
  int m = lane & 15, g = lane >> 4;
  int row0 = (blockIdx.x*4 + wave)*16;
  bf8_t a[4];
  #pragma unroll
  for (int ks = 0; ks < 4; ks++)
    a[ks] = *(const bf8_t*)(A + (size_t)(row0 + m)*CDIM + 8*g + 32*ks);
  f4_t acc[8];
  mfma_row(a, Wt, m, g, acc);
  #pragma unroll
  for (int ct = 0; ct < 8; ct++){
    int col = ct*16 + m;
    float bv = b2f(bias[col]);
    #pragma unroll
    for (int r = 0; r < 4; r++){
      size_t oi = (size_t)(row0 + 4*g + r)*CDIM + col;
      float v = acc[ct][r] + bv;
      if (f) ((bf16*)outp)[oi]  = f2b(v);
      else   ((float*)outp)[oi] = v;
    }
  }
}

// ---------------------------------------------------------------------------
extern "C" void kernel_launch(void* const* d_in, const int* in_sizes, int n_in,
                              void* d_out, int out_size, void* d_ws, size_t ws_size,
                              hipStream_t stream)
{
  const void* x   = d_in[0];
  const void* rel = d_in[1];
  const void* Wq  = d_in[2];
  const void* bq  = d_in[3];
  const void* Wk  = d_in[4];
  const void* bk  = d_in[5];
  const void* Wv  = d_in[6];
  const void* bv  = d_in[7];
  const void* cw  = d_in[8];
  const void* cb  = d_in[9];
  const void* gam = d_in[10];
  const void* bet = d_in[11];
  const void* mea = d_in[12];
  const void* var = d_in[13];
  const void* Wp  = d_in[14];
  const void* bp  = d_in[15];

  char* w = (char*)d_ws;
  char* wend = (char*)d_ws + ws_size;
  auto alloc = [&](size_t bytes){
    char* p = w; w += (bytes + 255) & ~(size_t)255; return p;
  };
  bf16* Wqt = (bf16*)alloc(128*128*sizeof(bf16));
  bf16* Wkt = (bf16*)alloc(128*128*sizeof(bf16));
  bf16* Wvt = (bf16*)alloc(128*128*sizeof(bf16));
  bf16* Wpt = (bf16*)alloc(128*128*sizeof(bf16));
  bf16* bqs = (bf16*)alloc(128*sizeof(bf16));
  bf16* bks = (bf16*)alloc(128*sizeof(bf16));
  bf16* bvs = (bf16*)alloc(128*sizeof(bf16));
  bf16* bps = (bf16*)alloc(128*sizeof(bf16));
  float* cwf    = (float*)alloc(512*sizeof(float));
  float* inv    = (float*)alloc(128*sizeof(float));
  float* shift2 = (float*)alloc(128*sizeof(float));
  bf16* xr   = (bf16*)alloc((size_t)BATCH*NKV*CDIM*sizeof(bf16));
  bf16* kbf2 = (bf16*)alloc((size_t)BATCH*NKVP*CDIM*sizeof(bf16));
  bf16* vtb2 = (bf16*)alloc((size_t)BATCH*NHEAD*HD*NKVP*sizeof(bf16));
  bf16* obf  = (bf16*)alloc((size_t)BATCH*NQ*CDIM*sizeof(bf16));
  bf16* relb = (bf16*)alloc((size_t)NHEAD*NQT16*NCT*256*sizeof(bf16)); // 22.5 MB
  size_t qbf_bytes = (size_t)BATCH*NQ*CDIM*sizeof(bf16);
  bool use_q = (size_t)(wend - w) >= qbf_bytes + 256;
  bf16* qbf = use_q ? (bf16*)alloc(qbf_bytes) : nullptr;

  prep_kernel<<<256, 256, 0, stream>>>(Wq, Wk, Wv, Wp, var, cw, cb, gam, bet, mea,
                                       bq, bk, bv, bp,
                                       Wqt, Wkt, Wvt, Wpt, bqs, bks, bvs, bps,
                                       cwf, inv, shift2);
  fat_kernel<<<3136 + (use_q ? 392 : 0), 256, 0, stream>>>(
      x, var, cwf, inv, shift2, xr, Wqt, bqs, qbf);
  rel_kernel<<<NHEAD*NQT16, 256, 0, stream>>>(rel, var, relb);
  kv_kernel<<<224, 256, 0, stream>>>(xr, Wkt, Wvt, bks, bvs, kbf2, vtb2);

  dim3 ag(49, NHEAD, BATCH);
  if (use_q)
    attn_kernel<0><<<ag, 256, 0, stream>>>(qbf, x, Wqt, bqs, kbf2, vtb2, relb, var, d_out, obf);
  else
    attn_kernel<1><<<ag, 256, 0, stream>>>(qbf, x, Wqt, bqs, kbf2, vtb2, relb, var, d_out, obf);

  proj_kernel<<<392, 256, 0, stream>>>((const bf16*)d_out, obf, Wpt, bps, d_out, var);
}

// Round 10
// 250.861 us; speedup vs baseline: 1.1329x; 1.1329x over previous
//
#include <hip/hip_runtime.h>
#include <hip/hip_bf16.h>

#define BATCH 8
#define NQ 3136
#define CDIM 128
#define NHEAD 4
#define HD 32
#define NKV 784
#define HIMG 56
#define SCALE 0.17677669529663687f
#define L2E 1.44269504f

typedef __attribute__((ext_vector_type(8))) short bf8_t;   // 8 x bf16 (4 VGPRs)
typedef __attribute__((ext_vector_type(4))) float f4_t;    // 4 x fp32

using bf16 = __hip_bfloat16;
using u16  = unsigned short;

static __device__ __forceinline__ float b2f(bf16 v){ return __bfloat162float(v); }
static __device__ __forceinline__ bf16  f2b(float v){ return __float2bfloat16(v); }
static __device__ __forceinline__ short f2s(float v){
  union { bf16 b; short s; } u; u.b = f2b(v); return u.s;
}
static __device__ __forceinline__ float ld1(const void* p, size_t i, int f){
  return f ? b2f(((const bf16*)p)[i]) : ((const float*)p)[i];
}
static __device__ __forceinline__ bf8_t ld8(const void* p, size_t i, int f){
  if (f) return *(const bf8_t*)((const bf16*)p + i);
  const float* fp = (const float*)p + i;
  float4 a = *(const float4*)fp;
  float4 b = *(const float4*)(fp + 4);
  bf8_t r;
  r[0]=f2s(a.x); r[1]=f2s(a.y); r[2]=f2s(a.z); r[3]=f2s(a.w);
  r[4]=f2s(b.x); r[5]=f2s(b.y); r[6]=f2s(b.z); r[7]=f2s(b.w);
  return r;
}
static __device__ __forceinline__ int detect_flag(const void* var_raw){
  const u16* h = (const u16*)var_raw;
  int lane = threadIdx.x & 63;
  bool ok = true;
  #pragma unroll
  for (int t = 0; t < 2; t++){
    union { u16 u; bf16 b; } cv; cv.u = h[lane + 64*t];
    float v = b2f(cv.b);
    ok = ok && (v > 0.3f) && (v < 1.7f);
  }
  return (__ballot(ok) == ~0ull) ? 1 : 0;
}

static __device__ __forceinline__ void mfma_row(
    const bf8_t a[4], const bf16* __restrict__ Wt, int m, int g, f4_t acc[8])
{
  #pragma unroll
  for (int ct = 0; ct < 8; ct++){
    f4_t c = {0.f,0.f,0.f,0.f};
    const bf16* bp = Wt + (size_t)(ct*16 + m)*CDIM + 8*g;
    #pragma unroll
    for (int ks = 0; ks < 4; ks++){
      bf8_t b = *(const bf8_t*)(bp + 32*ks);
      c = __builtin_amdgcn_mfma_f32_16x16x32_bf16(a[ks], b, c, 0,0,0);
    }
    acc[ct] = c;
  }
}

// ---------------------------------------------------------------------------
// prep: weight transposes; Wqt/bqs carry SCALE*L2E (log2-domain QK);
// small params; BN fold.
// ---------------------------------------------------------------------------
__global__ __launch_bounds__(256) void prep_kernel(
    const void* __restrict__ Wq, const void* __restrict__ Wk,
    const void* __restrict__ Wv, const void* __restrict__ Wp,
    const void* __restrict__ var, const void* __restrict__ cw,
    const void* __restrict__ cb, const void* __restrict__ gam,
    const void* __restrict__ bet, const void* __restrict__ mea,
    const void* __restrict__ bq, const void* __restrict__ bk,
    const void* __restrict__ bv, const void* __restrict__ bp,
    bf16* __restrict__ Wqt, bf16* __restrict__ Wkt,
    bf16* __restrict__ Wvt, bf16* __restrict__ Wpt,
    bf16* __restrict__ bqs, bf16* __restrict__ bks,
    bf16* __restrict__ bvs, bf16* __restrict__ bps,
    float* __restrict__ cwf, float* __restrict__ inv, float* __restrict__ shift2)
{
  int f = detect_flag(var);
  int idx = blockIdx.x*256 + threadIdx.x;
  int mat = idx >> 14;
  int e   = idx & 16383;
  int o = e >> 7, i = e & 127;
  const void* src; bf16* dst; float s = 1.f;
  if      (mat == 0){ src = Wq; dst = Wqt; s = SCALE * L2E; }
  else if (mat == 1){ src = Wk; dst = Wkt; }
  else if (mat == 2){ src = Wv; dst = Wvt; }
  else              { src = Wp; dst = Wpt; }
  dst[e] = f2b(ld1(src, (size_t)i*128 + o, f) * s);

  if (blockIdx.x == 0){
    int t = threadIdx.x;
    cwf[t]       = ld1(cw, t, f);
    cwf[t + 256] = ld1(cw, t + 256, f);
    if (t < 128){
      bqs[t] = f2b(ld1(bq, t, f) * SCALE * L2E);
      bks[t] = f2b(ld1(bk, t, f));
      bvs[t] = f2b(ld1(bv, t, f));
      bps[t] = f2b(ld1(bp, t, f));
      float iv = ld1(gam, t, f) * rsqrtf(ld1(var, t, f) + 1e-5f);
      inv[t] = iv;
      shift2[t] = ld1(bet, t, f) - ld1(mea, t, f) * iv + ld1(cb, t, f) * iv;
    }
  }
}

// ---------------------------------------------------------------------------
// fat: [0,3136) spatial reduction (conv2x2s2 + BN) -> xr
//      [3136,3528) Q projection GEMM -> qbf
// ---------------------------------------------------------------------------
__global__ __launch_bounds__(256) void fat_kernel(
    const void* __restrict__ x, const void* __restrict__ var,
    const float* __restrict__ cwf, const float* __restrict__ inv,
    const float* __restrict__ shift2, bf16* __restrict__ xr,
    const bf16* __restrict__ Wqt, const bf16* __restrict__ bqs,
    bf16* __restrict__ qbf)
{
  int f = detect_flag(var);
  if (blockIdx.x < 3136){
    int idx = blockIdx.x*256 + threadIdx.x;
    int c  = idx & 127;
    int t  = idx >> 7;
    int b  = t / NKV;
    int kv = t - b*NKV;
    int i = kv/28, j = kv - i*28;
    size_t base = (size_t)(b*NQ + 2*i*HIMG + 2*j)*CDIM + c;
    float acc = ld1(x, base, f)                   * cwf[c*4 + 0]
              + ld1(x, base + CDIM, f)            * cwf[c*4 + 1]
              + ld1(x, base + HIMG*CDIM, f)       * cwf[c*4 + 2]
              + ld1(x, base + HIMG*CDIM + CDIM, f)* cwf[c*4 + 3];
    xr[idx] = f2b(acc * inv[c] + shift2[c]);
  } else {
    int wave = threadIdx.x >> 6, lane = threadIdx.x & 63;
    int m = lane & 15, g = lane >> 4;
    int task = (blockIdx.x - 3136)*4 + wave;
    int row0 = task*16;
    bf8_t a[4];
    #pragma unroll
    for (int ks = 0; ks < 4; ks++)
      a[ks] = ld8(x, (size_t)(row0 + m)*CDIM + 8*g + 32*ks, f);
    f4_t acc[8];
    mfma_row(a, Wqt, m, g, acc);
    #pragma unroll
    for (int ct = 0; ct < 8; ct++){
      int col = ct*16 + m;
      float bv = b2f(bqs[col]);
      #pragma unroll
      for (int r = 0; r < 4; r++)
        qbf[(size_t)(row0 + 4*g + r)*CDIM + col] = f2b(acc[ct][r] + bv);
    }
  }
}

// ---------------------------------------------------------------------------
// kv: blocks [0,98) K-proj -> kbf (B,NKV,C); [98,196) V-proj -> vtb (B,H,D,NKV)
// ---------------------------------------------------------------------------
__global__ __launch_bounds__(256) void kv_kernel(
    const bf16* __restrict__ xr,
    const bf16* __restrict__ Wkt, const bf16* __restrict__ Wvt,
    const bf16* __restrict__ bks, const bf16* __restrict__ bvs,
    bf16* __restrict__ kbf, bf16* __restrict__ vtb)
{
  int wave = threadIdx.x >> 6, lane = threadIdx.x & 63;
  int m = lane & 15, g = lane >> 4;
  bool isK = blockIdx.x < 98;
  int bx = isK ? blockIdx.x : blockIdx.x - 98;
  int row0 = (bx*4 + wave)*16;
  bf8_t a[4];
  #pragma unroll
  for (int ks = 0; ks < 4; ks++)
    a[ks] = *(const bf8_t*)(xr + (size_t)(row0 + m)*CDIM + 8*g + 32*ks);
  f4_t acc[8];
  mfma_row(a, isK ? Wkt : Wvt, m, g, acc);

  if (isK){
    #pragma unroll
    for (int ct = 0; ct < 8; ct++){
      int col = ct*16 + m;
      float bv = b2f(bks[col]);
      #pragma unroll
      for (int r = 0; r < 4; r++)
        kbf[(size_t)(row0 + 4*g + r)*CDIM + col] = f2b(acc[ct][r] + bv);
    }
  } else {
    int b   = row0 / NKV;
    int kv0 = row0 - b*NKV + 4*g;
    #pragma unroll
    for (int ct = 0; ct < 8; ct++){
      int col = ct*16 + m;
      float bv = b2f(bvs[col]);
      int h = col >> 5, d = col & 31;
      union { bf16 hh[4]; uint2 u; } pk;
      #pragma unroll
      for (int r = 0; r < 4; r++) pk.hh[r] = f2b(acc[ct][r] + bv);
      *(uint2*)(vtb + (size_t)((b*NHEAD + h)*HD + d)*NKV + kv0) = pk.u;
    }
  }
}

// ---------------------------------------------------------------------------
// attention: 2 q-tiles (32 rows) per wave sharing K and V fragments.
// Log2-domain fixed-base softmax (p = exp2(qk*scale*l2e + rel*l2e); base
// cancels in O/l). rel read directly from global (fp32 or bf16), *L2E in
// VALU, injected as the QK MFMA C-operand. Wave-private P-LDS, no barriers.
// Tail (kv 768..783): single 16-tile; lanes g>=2 zero A/V fragments.
// ---------------------------------------------------------------------------
template<int QF>
__global__ __launch_bounds__(256) void attn_kernel(
    const bf16* __restrict__ qbf, const void* __restrict__ x,
    const bf16* __restrict__ Wqt, const bf16* __restrict__ bqs,
    const bf16* __restrict__ kb, const bf16* __restrict__ vtb,
    const void* __restrict__ rel, const void* __restrict__ var,
    void* __restrict__ dout, bf16* __restrict__ obf)
{
  int f = detect_flag(var);
  int wave = threadIdx.x >> 6, lane = threadIdx.x & 63;
  int m = lane & 15, g = lane >> 4;
  int b = blockIdx.z, h = blockIdx.y;
  int task = blockIdx.x*4 + wave;              // 0..99; 98,99 idle
  if (task >= 98) return;
  int qrow0 = task*32;                         // tiles: qrow0, qrow0+16

  __shared__ bf16 Plds[4][2][16*136];
  bf16* plA = Plds[wave][0];
  bf16* plB = Plds[wave][1];

  bf8_t q8a, q8b;
  if constexpr (QF == 0){
    q8a = *(const bf8_t*)(qbf + (size_t)(b*NQ + qrow0 + m)*CDIM + h*HD + 8*g);
    q8b = *(const bf8_t*)(qbf + (size_t)(b*NQ + qrow0 + 16 + m)*CDIM + h*HD + 8*g);
  } else {
    const bf16* wp0 = Wqt + (size_t)(h*HD + m)*CDIM + 8*g;
    const bf16* wp1 = Wqt + (size_t)(h*HD + 16 + m)*CDIM + 8*g;
    float bv0 = b2f(bqs[h*HD + m]);
    float bv1 = b2f(bqs[h*HD + 16 + m]);
    #pragma unroll
    for (int tile = 0; tile < 2; tile++){
      bf8_t xa[4];
      #pragma unroll
      for (int ks = 0; ks < 4; ks++)
        xa[ks] = ld8(x, (size_t)(b*NQ + qrow0 + tile*16 + m)*CDIM + 8*g + 32*ks, f);
      f4_t qc0 = {0.f,0.f,0.f,0.f}, qc1 = {0.f,0.f,0.f,0.f};
      #pragma unroll
      for (int ks = 0; ks < 4; ks++){
        bf8_t w0 = *(const bf8_t*)(wp0 + 32*ks);
        bf8_t w1 = *(const bf8_t*)(wp1 + 32*ks);
        qc0 = __builtin_amdgcn_mfma_f32_16x16x32_bf16(xa[ks], w0, qc0, 0,0,0);
        qc1 = __builtin_amdgcn_mfma_f32_16x16x32_bf16(xa[ks], w1, qc1, 0,0,0);
      }
      bf16* pl = tile ? plB : plA;
      #pragma unroll
      for (int r = 0; r < 4; r++){
        pl[(4*g + r)*136 + m]      = f2b(qc0[r] + bv0);
        pl[(4*g + r)*136 + 16 + m] = f2b(qc1[r] + bv1);
      }
      if (tile == 0) q8a = *(const bf8_t*)(plA + m*136 + 8*g);
      else           q8b = *(const bf8_t*)(plB + m*136 + 8*g);
    }
  }

  const bf16* kbase = kb  + ((size_t)b*NKV + m)*CDIM + h*HD + 8*g;
  const bf16* vb0   = vtb + ((size_t)(b*NHEAD + h)*HD + m)*NKV;
  const bf16* vb1   = vb0 + (size_t)16*NKV;
  size_t ria = ((size_t)h*NQ + qrow0 + 4*g)*NKV + m;
  size_t rib = ria + (size_t)16*NKV;

  float la[4] = {0.f,0.f,0.f,0.f}, lb[4] = {0.f,0.f,0.f,0.f};
  f4_t Oa0 = {0.f,0.f,0.f,0.f}, Oa1 = {0.f,0.f,0.f,0.f};
  f4_t Ob0 = {0.f,0.f,0.f,0.f}, Ob1 = {0.f,0.f,0.f,0.f};

  #pragma unroll 1
  for (int kv0 = 0; kv0 < 768; kv0 += 128){
    #pragma unroll
    for (int t = 0; t < 8; t++){
      int kvt = kv0 + t*16;
      bf8_t k8 = *(const bf8_t*)(kbase + (size_t)kvt*CDIM);
      f4_t ra, rb;
      #pragma unroll
      for (int r = 0; r < 4; r++){
        ra[r] = ld1(rel, ria + (size_t)r*NKV + kvt, f) * L2E;
        rb[r] = ld1(rel, rib + (size_t)r*NKV + kvt, f) * L2E;
      }
      f4_t sa = __builtin_amdgcn_mfma_f32_16x16x32_bf16(q8a, k8, ra, 0,0,0);
      f4_t sb = __builtin_amdgcn_mfma_f32_16x16x32_bf16(q8b, k8, rb, 0,0,0);
      #pragma unroll
      for (int r = 0; r < 4; r++){
        float pa = exp2f(sa[r]); la[r] += pa;
        plA[(4*g + r)*136 + t*16 + m] = f2b(pa);
        float pb = exp2f(sb[r]); lb[r] += pb;
        plB[(4*g + r)*136 + t*16 + m] = f2b(pb);
      }
    }
    #pragma unroll
    for (int ks = 0; ks < 4; ks++){
      bf8_t a8a = *(const bf8_t*)(plA + m*136 + ks*32 + 8*g);
      bf8_t a8b = *(const bf8_t*)(plB + m*136 + ks*32 + 8*g);
      bf8_t v0 = *(const bf8_t*)(vb0 + kv0 + ks*32 + 8*g);
      bf8_t v1 = *(const bf8_t*)(vb1 + kv0 + ks*32 + 8*g);
      Oa0 = __builtin_amdgcn_mfma_f32_16x16x32_bf16(a8a, v0, Oa0, 0,0,0);
      Oa1 = __builtin_amdgcn_mfma_f32_16x16x32_bf16(a8a, v1, Oa1, 0,0,0);
      Ob0 = __builtin_amdgcn_mfma_f32_16x16x32_bf16(a8b, v0, Ob0, 0,0,0);
      Ob1 = __builtin_amdgcn_mfma_f32_16x16x32_bf16(a8b, v1, Ob1, 0,0,0);
    }
  }
  // tail: kv 768..783 (one 16-tile)
  {
    bf8_t k8 = *(const bf8_t*)(kbase + (size_t)768*CDIM);
    f4_t ra, rb;
    #pragma unroll
    for (int r = 0; r < 4; r++){
      ra[r] = ld1(rel, ria + (size_t)r*NKV + 768, f) * L2E;
      rb[r] = ld1(rel, rib + (size_t)r*NKV + 768, f) * L2E;
    }
    f4_t sa = __builtin_amdgcn_mfma_f32_16x16x32_bf16(q8a, k8, ra, 0,0,0);
    f4_t sb = __builtin_amdgcn_mfma_f32_16x16x32_bf16(q8b, k8, rb, 0,0,0);
    #pragma unroll
    for (int r = 0; r < 4; r++){
      float pa = exp2f(sa[r]); la[r] += pa;
      plA[(4*g + r)*136 + m] = f2b(pa);
      float pb = exp2f(sb[r]); lb[r] += pb;
      plB[(4*g + r)*136 + m] = f2b(pb);
    }
    bf8_t a8a = *(const bf8_t*)(plA + m*136 + 8*g);
    bf8_t a8b = *(const bf8_t*)(plB + m*136 + 8*g);
    bf8_t v0, v1;
    if (g >= 2){
      bf8_t z8 = {0,0,0,0,0,0,0,0};
      a8a = z8; a8b = z8; v0 = z8; v1 = z8;
    } else {
      v0 = *(const bf8_t*)(vb0 + 768 + 8*g);
      v1 = *(const bf8_t*)(vb1 + 768 + 8*g);
    }
    Oa0 = __builtin_amdgcn_mfma_f32_16x16x32_bf16(a8a, v0, Oa0, 0,0,0);
    Oa1 = __builtin_amdgcn_mfma_f32_16x16x32_bf16(a8a, v1, Oa1, 0,0,0);
    Ob0 = __builtin_amdgcn_mfma_f32_16x16x32_bf16(a8b, v0, Ob0, 0,0,0);
    Ob1 = __builtin_amdgcn_mfma_f32_16x16x32_bf16(a8b, v1, Ob1, 0,0,0);
  }

  #pragma unroll
  for (int xm = 1; xm < 16; xm <<= 1){
    #pragma unroll
    for (int r = 0; r < 4; r++){
      la[r] += __shfl_xor(la[r], xm, 64);
      lb[r] += __shfl_xor(lb[r], xm, 64);
    }
  }
  bf16* ob = f ? (bf16*)dout : obf;
  size_t orowA = (size_t)(b*NQ + qrow0 + 4*g);
  size_t orowB = orowA + 16;
  #pragma unroll
  for (int r = 0; r < 4; r++){
    float ia = 1.0f / la[r];
    float ib = 1.0f / lb[r];
    ob[(orowA + r)*CDIM + h*HD + m]      = f2b(Oa0[r] * ia);
    ob[(orowA + r)*CDIM + h*HD + 16 + m] = f2b(Oa1[r] * ia);
    ob[(orowB + r)*CDIM + h*HD + m]      = f2b(Ob0[r] * ib);
    ob[(orowB + r)*CDIM + h*HD + 16 + m] = f2b(Ob1[r] * ib);
  }
}

// ---------------------------------------------------------------------------
// final projection: in-place (bf16 mode) | obf -> fp32 d_out (fp32 mode).
// ---------------------------------------------------------------------------
__global__ __launch_bounds__(256) void proj_kernel(
    const bf16* A0, const bf16* A1, const bf16* __restrict__ Wt,
    const bf16* __restrict__ bias, void* outp, const void* __restrict__ var)
{
  int f = detect_flag(var);
  const bf16* A = f ? A0 : A1;
  int wave = threadIdx.x >> 6, lane = threadIdx.x & 63;
  int m = lane & 15, g = lane >> 4;
  int row0 = (blockIdx.x*4 + wave)*16;
  bf8_t a[4];
  #pragma unroll
  for (int ks = 0; ks < 4; ks++)
    a[ks] = *(const bf8_t*)(A + (size_t)(row0 + m)*CDIM + 8*g + 32*ks);
  f4_t acc[8];
  mfma_row(a, Wt, m, g, acc);
  #pragma unroll
  for (int ct = 0; ct < 8; ct++){
    int col = ct*16 + m;
    float bv = b2f(bias[col]);
    #pragma unroll
    for (int r = 0; r < 4; r++){
      size_t oi = (size_t)(row0 + 4*g + r)*CDIM + col;
      float v = acc[ct][r] + bv;
      if (f) ((bf16*)outp)[oi]  = f2b(v);
      else   ((float*)outp)[oi] = v;
    }
  }
}

// ---------------------------------------------------------------------------
extern "C" void kernel_launch(void* const* d_in, const int* in_sizes, int n_in,
                              void* d_out, int out_size, void* d_ws, size_t ws_size,
                              hipStream_t stream)
{
  const void* x   = d_in[0];
  const void* rel = d_in[1];
  const void* Wq  = d_in[2];
  const void* bq  = d_in[3];
  const void* Wk  = d_in[4];
  const void* bk  = d_in[5];
  const void* Wv  = d_in[6];
  const void* bv  = d_in[7];
  const void* cw  = d_in[8];
  const void* cb  = d_in[9];
  const void* gam = d_in[10];
  const void* bet = d_in[11];
  const void* mea = d_in[12];
  const void* var = d_in[13];
  const void* Wp  = d_in[14];
  const void* bp  = d_in[15];

  char* w = (char*)d_ws;
  char* wend = (char*)d_ws + ws_size;
  auto alloc = [&](size_t bytes){
    char* p = w; w += (bytes + 255) & ~(size_t)255; return p;
  };
  bf16* Wqt = (bf16*)alloc(128*128*sizeof(bf16));
  bf16* Wkt = (bf16*)alloc(128*128*sizeof(bf16));
  bf16* Wvt = (bf16*)alloc(128*128*sizeof(bf16));
  bf16* Wpt = (bf16*)alloc(128*128*sizeof(bf16));
  bf16* bqs = (bf16*)alloc(128*sizeof(bf16));
  bf16* bks = (bf16*)alloc(128*sizeof(bf16));
  bf16* bvs = (bf16*)alloc(128*sizeof(bf16));
  bf16* bps = (bf16*)alloc(128*sizeof(bf16));
  float* cwf    = (float*)alloc(512*sizeof(float));
  float* inv    = (float*)alloc(128*sizeof(float));
  float* shift2 = (float*)alloc(128*sizeof(float));
  bf16* xr  = (bf16*)alloc((size_t)BATCH*NKV*CDIM*sizeof(bf16));
  bf16* kbf = (bf16*)alloc((size_t)BATCH*NKV*CDIM*sizeof(bf16));
  bf16* vtb = (bf16*)alloc((size_t)BATCH*NKV*CDIM*sizeof(bf16));
  bf16* obf = (bf16*)alloc((size_t)BATCH*NQ*CDIM*sizeof(bf16)); // fp32-mode attn out
  size_t qbf_bytes = (size_t)BATCH*NQ*CDIM*sizeof(bf16);
  bool use_q = (size_t)(wend - w) >= qbf_bytes + 256;
  bf16* qbf = use_q ? (bf16*)alloc(qbf_bytes) : nullptr;

  prep_kernel<<<256, 256, 0, stream>>>(Wq, Wk, Wv, Wp, var, cw, cb, gam, bet, mea,
                                       bq, bk, bv, bp,
                                       Wqt, Wkt, Wvt, Wpt, bqs, bks, bvs, bps,
                                       cwf, inv, shift2);
  fat_kernel<<<3136 + (use_q ? 392 : 0), 256, 0, stream>>>(
      x, var, cwf, inv, shift2, xr, Wqt, bqs, qbf);
  kv_kernel<<<196, 256, 0, stream>>>(xr, Wkt, Wvt, bks, bvs, kbf, vtb);

  dim3 ag(25, NHEAD, BATCH);
  if (use_q)
    attn_kernel<0><<<ag, 256, 0, stream>>>(qbf, x, Wqt, bqs, kbf, vtb, rel, var, d_out, obf);
  else
    attn_kernel<1><<<ag, 256, 0, stream>>>(qbf, x, Wqt, bqs, kbf, vtb, rel, var, d_out, obf);

  proj_kernel<<<392, 256, 0, stream>>>((const bf16*)d_out, obf, Wpt, bps, d_out, var);
}